// Round 3
// baseline (23308.009 us; speedup 1.0000x reference)
//
#include <hip/hip_runtime.h>
#include <hip/hip_bf16.h>

#define Bn  2
#define Nn  768
#define Dh  32
#define DMm 64
#define KK  16
#define TPB 256

__global__ __launch_bounds__(TPB, 2) void egnn_fused(
    const float* __restrict__ X,  const float* __restrict__ H,
    const float* __restrict__ e0W, const float* __restrict__ e0b,
    const float* __restrict__ e0s, const float* __restrict__ e0t,
    const float* __restrict__ e1W, const float* __restrict__ e1b,
    const float* __restrict__ e1s, const float* __restrict__ e1t,
    const float* __restrict__ c0W, const float* __restrict__ c0b,
    const float* __restrict__ c0s, const float* __restrict__ c0t,
    const float* __restrict__ c1W, const float* __restrict__ c1b,
    const float* __restrict__ c1s, const float* __restrict__ c1t,
    const float* __restrict__ n0W, const float* __restrict__ n0b,
    const float* __restrict__ n0s, const float* __restrict__ n0t,
    float* __restrict__ out)
{
    const int bid = blockIdx.x;          // 0 .. B*N-1
    const int b   = bid / Nn;
    const int i   = bid % Nn;
    const int tid = threadIdx.x;

    __shared__ float sW0[65 * DMm];      // e0W, scale-folded
    __shared__ float sW1[DMm * DMm];     // e1W, scale-folded
    __shared__ float sW2[DMm * DMm];     // c0W, scale-folded
    __shared__ float sW3[DMm];           // c1W, scale-folded
    __shared__ float sWn[(Dh + DMm) * Dh];
    __shared__ float sS0[DMm], sS1[DMm], sS2[DMm], sSn[Dh];
    __shared__ float sO1[DMm], sO2[DMm], sOn[Dh];
    __shared__ float sBase0[DMm];
    __shared__ float sHi[Dh];
    __shared__ float sXi[3];
    __shared__ float sD2[Nn];
    __shared__ int   sKnn[KK];
    __shared__ float sMnode[DMm];
    __shared__ float sXacc[3];
    __shared__ float sC1off[1];

    // ---- stage 1: scales / offsets / center point ----
    if (tid < DMm) {
        sS0[tid] = e0s[tid];
        float s1 = e1s[tid];
        float s2 = c0s[tid];
        sS1[tid] = s1;
        sS2[tid] = s2;
        sO1[tid] = fmaf(e1b[tid], s1, e1t[tid]);
        sO2[tid] = fmaf(c0b[tid], s2, c0t[tid]);
        sMnode[tid] = 0.f;
    }
    if (tid < Dh) {
        float sn = n0s[tid];
        sSn[tid] = sn;
        sOn[tid] = fmaf(n0b[tid], sn, n0t[tid]);
        sHi[tid] = H[(size_t)(b * Nn + i) * Dh + tid];
    }
    if (tid < 3) {
        sXi[tid]  = X[(size_t)(b * Nn + i) * 3 + tid];
        sXacc[tid] = 0.f;
    }
    if (tid == 0) {
        sC1off[0] = fmaf(c1b[0], c1s[0], c1t[0]);
    }
    __syncthreads();

    // ---- stage 2: weights -> fp32 LDS with BN scale folded into columns ----
    for (int k = tid; k < 65 * DMm; k += TPB)
        sW0[k] = e0W[k] * sS0[k & 63];
    for (int k = tid; k < DMm * DMm; k += TPB)
        sW1[k] = e1W[k] * sS1[k & 63];
    for (int k = tid; k < DMm * DMm; k += TPB)
        sW2[k] = c0W[k] * sS2[k & 63];
    if (tid < DMm)
        sW3[tid] = c1W[tid] * c1s[0];
    for (int k = tid; k < (Dh + DMm) * Dh; k += TPB)
        sWn[k] = n0W[k] * sSn[k & 31];
    __syncthreads();

    // ---- stage 3: base0 (h_i half of e0, constant over j) + d2 over all j ----
    if (tid < DMm) {
        float z = 0.f;
        #pragma unroll
        for (int c = 0; c < Dh; ++c)
            z = fmaf(sHi[c], sW0[(Dh + c) * DMm + tid], z);
        sBase0[tid] = z + fmaf(e0b[tid], sS0[tid], e0t[tid]);
    }
    for (int j = tid; j < Nn; j += TPB) {
        float dx = X[(size_t)(b * Nn + j) * 3 + 0] - sXi[0];
        float dy = X[(size_t)(b * Nn + j) * 3 + 1] - sXi[1];
        float dz = X[(size_t)(b * Nn + j) * 3 + 2] - sXi[2];
        // non-fused fp32, matches numpy mul-then-add for exact knn ranking
        sD2[j] = __fadd_rn(__fadd_rn(__fmul_rn(dx, dx), __fmul_rn(dy, dy)),
                           __fmul_rn(dz, dz));
    }
    __syncthreads();

    // ---- stage 4: K smallest d2 (tie -> lower index), wave 0 only ----
    // d2 values held in registers; exclusions applied locally from the
    // broadcast winner (no LDS re-read -> no stale-cache hazard).
    if (tid < 64) {
        float v[Nn / 64];
        #pragma unroll
        for (int k = 0; k < Nn / 64; ++k) v[k] = sD2[tid + (k << 6)];
        for (int r = 0; r < KK; ++r) {
            float bv = 3.4e38f; int bidx = Nn;
            #pragma unroll
            for (int k = 0; k < Nn / 64; ++k) {
                if (v[k] < bv) { bv = v[k]; bidx = tid + (k << 6); }
            }
            #pragma unroll
            for (int off = 32; off >= 1; off >>= 1) {
                float ov = __shfl_down(bv, off);
                int   oi = __shfl_down(bidx, off);
                if (ov < bv || (ov == bv && oi < bidx)) { bv = ov; bidx = oi; }
            }
            bidx = __shfl(bidx, 0);
            if (tid == 0) sKnn[r] = bidx;
            if ((bidx & 63) == tid) v[bidx >> 6] = 3.4e38f;
        }
    }
    __syncthreads();

    // ---- stage 5: main MLP loop over neighbors j ----
    float xacc0 = 0.f, xacc1 = 0.f, xacc2 = 0.f;
    for (int jj = 0; jj < Nn / TPB; ++jj) {
        const int j = tid + jj * TPB;

        float xj0 = X[(size_t)(b * Nn + j) * 3 + 0];
        float xj1 = X[(size_t)(b * Nn + j) * 3 + 1];
        float xj2 = X[(size_t)(b * Nn + j) * 3 + 2];
        float dx = xj0 - sXi[0], dy = xj1 - sXi[1], dz = xj2 - sXi[2];
        float d2 = __fadd_rn(__fadd_rn(__fmul_rn(dx, dx), __fmul_rn(dy, dy)),
                             __fmul_rn(dz, dz));

        // h_j : 32 f32 = 128B, aligned (row stride 128B)
        const float4* hp = reinterpret_cast<const float4*>(H + (size_t)(b * Nn + j) * Dh);
        float hj[Dh];
        #pragma unroll
        for (int q = 0; q < Dh / 4; ++q) {
            float4 v = hp[q];
            hj[4 * q + 0] = v.x; hj[4 * q + 1] = v.y;
            hj[4 * q + 2] = v.z; hj[4 * q + 3] = v.w;
        }

        // e0: a0 = relu( hj*W0[0:32] + d2*W0[64] + base0 )   (scale pre-folded)
        float a0[DMm];
        #pragma unroll
        for (int o = 0; o < DMm; ++o)
            a0[o] = fmaf(d2, sW0[64 * DMm + o], sBase0[o]);
        #pragma unroll
        for (int c = 0; c < Dh; ++c) {
            float fc = hj[c];
            #pragma unroll
            for (int o = 0; o < DMm; ++o)
                a0[o] = fmaf(fc, sW0[c * DMm + o], a0[o]);
        }
        #pragma unroll
        for (int o = 0; o < DMm; ++o) a0[o] = fmaxf(a0[o], 0.f);

        // e1 -> m_edge
        float a1[DMm];
        #pragma unroll
        for (int o = 0; o < DMm; ++o) a1[o] = sO1[o];
        #pragma unroll
        for (int c = 0; c < DMm; ++c) {
            float fc = a0[c];
            #pragma unroll
            for (int o = 0; o < DMm; ++o)
                a1[o] = fmaf(fc, sW1[c * DMm + o], a1[o]);
        }
        #pragma unroll
        for (int o = 0; o < DMm; ++o) a1[o] = fmaxf(a1[o], 0.f);

        // c0
        float a2[DMm];
        #pragma unroll
        for (int o = 0; o < DMm; ++o) a2[o] = sO2[o];
        #pragma unroll
        for (int c = 0; c < DMm; ++c) {
            float fc = a1[c];
            #pragma unroll
            for (int o = 0; o < DMm; ++o)
                a2[o] = fmaf(fc, sW2[c * DMm + o], a2[o]);
        }
        #pragma unroll
        for (int o = 0; o < DMm; ++o) a2[o] = fmaxf(a2[o], 0.f);

        // c1 -> scalar edge weight
        float w = sC1off[0];
        #pragma unroll
        for (int c = 0; c < DMm; ++c) w = fmaf(a2[c], sW3[c], w);
        w = fmaxf(w, 0.f);

        xacc0 = fmaf(w, dx, xacc0);
        xacc1 = fmaf(w, dy, xacc1);
        xacc2 = fmaf(w, dz, xacc2);

        // knn membership -> accumulate m_edge into m_node
        bool sel = false;
        #pragma unroll
        for (int r = 0; r < KK; ++r) sel = sel || (sKnn[r] == j);
        if (sel) {
            #pragma unroll
            for (int o = 0; o < DMm; ++o) atomicAdd(&sMnode[o], a1[o]);
        }
    }
    atomicAdd(&sXacc[0], xacc0);
    atomicAdd(&sXacc[1], xacc1);
    atomicAdd(&sXacc[2], xacc2);
    __syncthreads();

    // ---- stage 6: outputs (fp32, concatenated: x_update then h_update) ----
    if (tid < 3) {
        out[(size_t)(b * Nn + i) * 3 + tid] = sXi[tid] + sXacc[tid];
    }
    if (tid < Dh) {
        float z = sOn[tid];
        #pragma unroll
        for (int c = 0; c < Dh; ++c)
            z = fmaf(sHi[c], sWn[c * Dh + tid], z);
        #pragma unroll
        for (int c = 0; c < DMm; ++c)
            z = fmaf(sMnode[c], sWn[(Dh + c) * Dh + tid], z);
        out[(size_t)Bn * Nn * 3 + (size_t)(b * Nn + i) * Dh + tid] =
            fmaxf(z, 0.f);
    }
}

extern "C" void kernel_launch(void* const* d_in, const int* in_sizes, int n_in,
                              void* d_out, int out_size, void* d_ws, size_t ws_size,
                              hipStream_t stream) {
    const float* X   = (const float*)d_in[0];
    const float* H   = (const float*)d_in[1];
    const float* e0W = (const float*)d_in[2];
    const float* e0b = (const float*)d_in[3];
    const float* e0s = (const float*)d_in[4];
    const float* e0t = (const float*)d_in[5];
    const float* e1W = (const float*)d_in[6];
    const float* e1b = (const float*)d_in[7];
    const float* e1s = (const float*)d_in[8];
    const float* e1t = (const float*)d_in[9];
    const float* c0W = (const float*)d_in[10];
    const float* c0b = (const float*)d_in[11];
    const float* c0s = (const float*)d_in[12];
    const float* c0t = (const float*)d_in[13];
    const float* c1W = (const float*)d_in[14];
    const float* c1b = (const float*)d_in[15];
    const float* c1s = (const float*)d_in[16];
    const float* c1t = (const float*)d_in[17];
    const float* n0W = (const float*)d_in[18];
    const float* n0b = (const float*)d_in[19];
    const float* n0s = (const float*)d_in[20];
    const float* n0t = (const float*)d_in[21];
    float* out = (float*)d_out;

    dim3 grid(Bn * Nn);
    dim3 block(TPB);
    egnn_fused<<<grid, block, 0, stream>>>(X, H,
        e0W, e0b, e0s, e0t, e1W, e1b, e1s, e1t,
        c0W, c0b, c0s, c0t, c1W, c1b, c1s, c1t,
        n0W, n0b, n0s, n0t, out);
}

// Round 4
// 212.575 us; speedup vs baseline: 109.6458x; 109.6458x over previous
//
#include <hip/hip_runtime.h>
#include <hip/hip_bf16.h>

#define Bn  2
#define Nn  768
#define Dh  32
#define DMm 64
#define KK  16
#define TPB 256
#define NT  (Nn / 16)      // 48? no: 768/16 = 48 ... per block tiles = 12? (see below)
// NOTE: per block we tile 768 j-rows into 12 tiles of 16 handled by 4 waves.
#define NTILES 48          // unused guard
#define SA 80              // a1 staging row stride (elements); 160B keeps 16B alignment

typedef __bf16 bf16x8 __attribute__((ext_vector_type(8)));
typedef float  f32x4  __attribute__((ext_vector_type(4)));

// ---------------- phase 1: G1 = h @ W0a*s0 (bf16), G2 = h @ W0b*s0 + off0 (fp32)
__global__ __launch_bounds__(TPB) void egnn_pre(
    const float* __restrict__ H,  const float* __restrict__ e0W,
    const float* __restrict__ e0b, const float* __restrict__ e0s,
    const float* __restrict__ e0t,
    __bf16* __restrict__ G1, float* __restrict__ G2)
{
    __shared__ float sWa[Dh * DMm], sWb[Dh * DMm], sOff[DMm], sH[32 * Dh];
    const int tid = threadIdx.x;
    for (int k = tid; k < Dh * DMm; k += TPB) {
        float s = e0s[k & 63];
        sWa[k] = e0W[k] * s;
        sWb[k] = e0W[Dh * DMm + k] * s;
    }
    if (tid < DMm) sOff[tid] = fmaf(e0b[tid], e0s[tid], e0t[tid]);
    const int row0 = blockIdx.x * 32;           // 48 blocks x 32 rows = 1536
    for (int k = tid; k < 32 * Dh; k += TPB) sH[k] = H[(size_t)row0 * Dh + k];
    __syncthreads();

    const int r = tid >> 3, g = tid & 7;        // row r, channel group g*8
    float g1[8], g2[8];
    #pragma unroll
    for (int e = 0; e < 8; ++e) { g1[e] = 0.f; g2[e] = sOff[g * 8 + e]; }
    #pragma unroll
    for (int d = 0; d < Dh; ++d) {
        float hv = sH[r * Dh + d];
        #pragma unroll
        for (int e = 0; e < 8; ++e) {
            g1[e] = fmaf(hv, sWa[d * DMm + g * 8 + e], g1[e]);
            g2[e] = fmaf(hv, sWb[d * DMm + g * 8 + e], g2[e]);
        }
    }
    const size_t row = row0 + r;
    bf16x8 o;
    #pragma unroll
    for (int e = 0; e < 8; ++e) o[e] = (__bf16)g1[e];
    *(bf16x8*)(G1 + row * DMm + g * 8) = o;
    float4 f0 = make_float4(g2[0], g2[1], g2[2], g2[3]);
    float4 f1 = make_float4(g2[4], g2[5], g2[6], g2[7]);
    *(float4*)(G2 + row * DMm + g * 8) = f0;
    *(float4*)(G2 + row * DMm + g * 8 + 4) = f1;
}

// ---------------- phase 2: per-(b,i) fused edge MLP via MFMA + knn + outputs
__global__ __launch_bounds__(TPB, 2) void egnn_main(
    const float* __restrict__ X,  const float* __restrict__ H,
    const float* __restrict__ e0W, const float* __restrict__ e0s,
    const float* __restrict__ e1W, const float* __restrict__ e1b,
    const float* __restrict__ e1s, const float* __restrict__ e1t,
    const float* __restrict__ c0W, const float* __restrict__ c0b,
    const float* __restrict__ c0s, const float* __restrict__ c0t,
    const float* __restrict__ c1W, const float* __restrict__ c1b,
    const float* __restrict__ c1s, const float* __restrict__ c1t,
    const float* __restrict__ n0W, const float* __restrict__ n0b,
    const float* __restrict__ n0s, const float* __restrict__ n0t,
    const __bf16* __restrict__ G1, const float* __restrict__ G2,
    float* __restrict__ out)
{
    const int bid = blockIdx.x;
    const int b = bid / Nn, i = bid % Nn;
    const int tid = threadIdx.x;
    const int wv = tid >> 6;            // wave 0..3
    const int lane = tid & 63;
    const int l15 = lane & 15;          // m (A) / n (B,C)
    const int q   = lane >> 4;          // quad

    __shared__ __bf16 sW1[DMm * DMm];   // e1W folded, [k][n]
    __shared__ __bf16 sW2[DMm * DMm];   // c0W folded
    __shared__ float  sWn[(Dh + DMm) * Dh];
    __shared__ float  sS1[DMm], sS2[DMm], sO1[DMm], sO2[DMm];
    __shared__ float  sw3[DMm], swd2[DMm];
    __shared__ float  sSn[Dh], sOn[Dh], sHi[Dh];
    __shared__ float  sD2[Nn];
    __shared__ float  sDX[Nn * 3];
    __shared__ float  sWj[Nn];
    __shared__ int    sKnn[KK];
    __shared__ char   sHit[Nn];
    __shared__ float  sMnode[DMm];
    __shared__ float  sXacc[3], sXi[3], sC1off[1];
    __shared__ __align__(16) __bf16 sA1[4][16 * SA];   // per-wave a1 staging

    // ---- step 1: scalars, d2/xdiff, clears ----
    if (tid < DMm) {
        float s1 = e1s[tid], s2 = c0s[tid];
        sS1[tid] = s1; sS2[tid] = s2;
        sO1[tid] = fmaf(e1b[tid], s1, e1t[tid]);
        sO2[tid] = fmaf(c0b[tid], s2, c0t[tid]);
        swd2[tid] = e0W[64 * DMm + tid] * e0s[tid];
        sw3[tid]  = c1W[tid] * c1s[0];
        sMnode[tid] = 0.f;
    }
    if (tid < Dh) {
        float sn = n0s[tid];
        sSn[tid] = sn;
        sOn[tid] = fmaf(n0b[tid], sn, n0t[tid]);
        sHi[tid] = H[(size_t)(b * Nn + i) * Dh + tid];
    }
    if (tid < 3) { sXi[tid] = X[(size_t)(b * Nn + i) * 3 + tid]; sXacc[tid] = 0.f; }
    if (tid == 0) sC1off[0] = fmaf(c1b[0], c1s[0], c1t[0]);
    {
        float xi0 = X[(size_t)(b * Nn + i) * 3 + 0];
        float xi1 = X[(size_t)(b * Nn + i) * 3 + 1];
        float xi2 = X[(size_t)(b * Nn + i) * 3 + 2];
        for (int j = tid; j < Nn; j += TPB) {
            float dx = X[(size_t)(b * Nn + j) * 3 + 0] - xi0;
            float dy = X[(size_t)(b * Nn + j) * 3 + 1] - xi1;
            float dz = X[(size_t)(b * Nn + j) * 3 + 2] - xi2;
            sDX[j * 3 + 0] = dx; sDX[j * 3 + 1] = dy; sDX[j * 3 + 2] = dz;
            sD2[j] = __fadd_rn(__fadd_rn(__fmul_rn(dx, dx), __fmul_rn(dy, dy)),
                               __fmul_rn(dz, dz));
            sHit[j] = 0;
        }
    }
    __syncthreads();

    // ---- step 3: fold weights into LDS ----
    for (int k = tid; k < DMm * DMm; k += TPB) {
        sW1[k] = (__bf16)(e1W[k] * sS1[k & 63]);
        sW2[k] = (__bf16)(c0W[k] * sS2[k & 63]);
    }
    for (int k = tid; k < (Dh + DMm) * Dh; k += TPB)
        sWn[k] = n0W[k] * sSn[k & 31];
    __syncthreads();

    // ---- step 4a: wave 0 does knn (register-resident, verified round-3 logic) ----
    if (tid < 64) {
        float v[Nn / 64];
        #pragma unroll
        for (int k = 0; k < Nn / 64; ++k) v[k] = sD2[tid + (k << 6)];
        for (int r = 0; r < KK; ++r) {
            float bv = 3.4e38f; int bidx = Nn;
            #pragma unroll
            for (int k = 0; k < Nn / 64; ++k)
                if (v[k] < bv) { bv = v[k]; bidx = tid + (k << 6); }
            #pragma unroll
            for (int off = 32; off >= 1; off >>= 1) {
                float ov = __shfl_down(bv, off);
                int   oi = __shfl_down(bidx, off);
                if (ov < bv || (ov == bv && oi < bidx)) { bv = ov; bidx = oi; }
            }
            bidx = __shfl(bidx, 0);
            if (tid == 0) sKnn[r] = bidx;
            if ((bidx & 63) == tid) v[bidx >> 6] = 3.4e38f;
        }
        if (tid < KK) sHit[sKnn[tid]] = 1;
    }

    // ---- step 4b: hoist per-lane constants + weight B-fragments ----
    bf16x8 w1f[2][4], w2f[2][4];
    #pragma unroll
    for (int s = 0; s < 2; ++s)
        #pragma unroll
        for (int t4 = 0; t4 < 4; ++t4) {
            bf16x8 f1, f2;
            #pragma unroll
            for (int e = 0; e < 8; ++e) {
                int k = s * 32 + q * 8 + e;
                f1[e] = sW1[k * DMm + t4 * 16 + l15];
                f2[e] = sW2[k * DMm + t4 * 16 + l15];
            }
            w1f[s][t4] = f1; w2f[s][t4] = f2;
        }
    float g2c[2][8], wd2c[2][8];
    #pragma unroll
    for (int s = 0; s < 2; ++s) {
        const float4* gp = (const float4*)(G2 + (size_t)(b * Nn + i) * DMm + s * 32 + q * 8);
        float4 a = gp[0], c = gp[1];
        g2c[s][0] = a.x; g2c[s][1] = a.y; g2c[s][2] = a.z; g2c[s][3] = a.w;
        g2c[s][4] = c.x; g2c[s][5] = c.y; g2c[s][6] = c.z; g2c[s][7] = c.w;
        #pragma unroll
        for (int e = 0; e < 8; ++e) wd2c[s][e] = swd2[s * 32 + q * 8 + e];
    }
    float o1c[4], o2c[4], w3c[4];
    #pragma unroll
    for (int t4 = 0; t4 < 4; ++t4) {
        o1c[t4] = sO1[t4 * 16 + l15];
        o2c[t4] = sO2[t4 * 16 + l15];
        w3c[t4] = sw3[t4 * 16 + l15];
    }
    __syncthreads();
    const float c1off = sC1off[0];

    // ---- step 5: j-tile loop (each wave: tiles wv, wv+4, wv+8) ----
    for (int t = wv; t < Nn / 16; t += 4) {
        const int base = t * 16;
        const int jm = base + l15;              // this lane's A-row j

        // build a0 A-fragments directly in registers
        float d2v = sD2[jm];
        bf16x8 a0f[2];
        #pragma unroll
        for (int s = 0; s < 2; ++s) {
            bf16x8 g1v = *(const bf16x8*)(G1 + (size_t)(b * Nn + jm) * DMm + s * 32 + q * 8);
            bf16x8 af;
            #pragma unroll
            for (int e = 0; e < 8; ++e) {
                float v = fmaf(d2v, wd2c[s][e], g2c[s][e]) + (float)g1v[e];
                af[e] = (__bf16)fmaxf(v, 0.f);
            }
            a0f[s] = af;
        }

        // e1 GEMM: a1 = relu(a0 @ W1' + o1)
        f32x4 acc[4];
        #pragma unroll
        for (int t4 = 0; t4 < 4; ++t4) acc[t4] = f32x4{0.f, 0.f, 0.f, 0.f};
        #pragma unroll
        for (int s = 0; s < 2; ++s)
            #pragma unroll
            for (int t4 = 0; t4 < 4; ++t4)
                acc[t4] = __builtin_amdgcn_mfma_f32_16x16x32_bf16(
                    a0f[s], w1f[s][t4], acc[t4], 0, 0, 0);
        #pragma unroll
        for (int t4 = 0; t4 < 4; ++t4)
            #pragma unroll
            for (int r = 0; r < 4; ++r) {
                float v = fmaxf(acc[t4][r] + o1c[t4], 0.f);
                acc[t4][r] = v;
                sA1[wv][(q * 4 + r) * SA + t4 * 16 + l15] = (__bf16)v;
            }
        // m_node accumulation for knn rows (fp32 C-frag, full precision)
        #pragma unroll
        for (int r = 0; r < 4; ++r) {
            if (sHit[base + q * 4 + r]) {
                #pragma unroll
                for (int t4 = 0; t4 < 4; ++t4)
                    atomicAdd(&sMnode[t4 * 16 + l15], acc[t4][r]);
            }
        }
        // re-read a1 as A-fragments (wave-local staging; waitcnt auto)
        bf16x8 a1f[2];
        #pragma unroll
        for (int s = 0; s < 2; ++s)
            a1f[s] = *(const bf16x8*)&sA1[wv][l15 * SA + s * 32 + q * 8];

        // c0 GEMM: a2 = relu(a1 @ W2' + o2); fused c1 dot
        f32x4 acc2[4];
        #pragma unroll
        for (int t4 = 0; t4 < 4; ++t4) acc2[t4] = f32x4{0.f, 0.f, 0.f, 0.f};
        #pragma unroll
        for (int s = 0; s < 2; ++s)
            #pragma unroll
            for (int t4 = 0; t4 < 4; ++t4)
                acc2[t4] = __builtin_amdgcn_mfma_f32_16x16x32_bf16(
                    a1f[s], w2f[s][t4], acc2[t4], 0, 0, 0);
        float p[4] = {0.f, 0.f, 0.f, 0.f};
        #pragma unroll
        for (int t4 = 0; t4 < 4; ++t4)
            #pragma unroll
            for (int r = 0; r < 4; ++r)
                p[r] = fmaf(fmaxf(acc2[t4][r] + o2c[t4], 0.f), w3c[t4], p[r]);
        // reduce over the 16 lanes of each quad
        #pragma unroll
        for (int mask = 1; mask <= 8; mask <<= 1)
            #pragma unroll
            for (int r = 0; r < 4; ++r)
                p[r] += __shfl_xor(p[r], mask);
        if (l15 < 4) {
            float pv = (l15 == 0) ? p[0] : (l15 == 1) ? p[1] : (l15 == 2) ? p[2] : p[3];
            sWj[base + q * 4 + l15] = fmaxf(pv + c1off, 0.f);
        }
    }
    __syncthreads();

    // ---- step 6: epilogue ----
    // x_update: xacc = sum_j w[j] * xdiff[j]
    {
        float xa0 = 0.f, xa1 = 0.f, xa2 = 0.f;
        for (int j = tid; j < Nn; j += TPB) {
            float wvv = sWj[j];
            xa0 = fmaf(wvv, sDX[j * 3 + 0], xa0);
            xa1 = fmaf(wvv, sDX[j * 3 + 1], xa1);
            xa2 = fmaf(wvv, sDX[j * 3 + 2], xa2);
        }
        #pragma unroll
        for (int off = 32; off >= 1; off >>= 1) {
            xa0 += __shfl_down(xa0, off);
            xa1 += __shfl_down(xa1, off);
            xa2 += __shfl_down(xa2, off);
        }
        if (lane == 0) {
            atomicAdd(&sXacc[0], xa0);
            atomicAdd(&sXacc[1], xa1);
            atomicAdd(&sXacc[2], xa2);
        }
    }
    __syncthreads();
    if (tid < 3)
        out[(size_t)(b * Nn + i) * 3 + tid] = sXi[tid] + sXacc[tid];
    if (tid < Dh) {
        float z = sOn[tid];
        #pragma unroll
        for (int c = 0; c < Dh; ++c)
            z = fmaf(sHi[c], sWn[c * Dh + tid], z);
        #pragma unroll
        for (int c = 0; c < DMm; ++c)
            z = fmaf(sMnode[c], sWn[(Dh + c) * Dh + tid], z);
        out[(size_t)Bn * Nn * 3 + (size_t)(b * Nn + i) * Dh + tid] = fmaxf(z, 0.f);
    }
}

extern "C" void kernel_launch(void* const* d_in, const int* in_sizes, int n_in,
                              void* d_out, int out_size, void* d_ws, size_t ws_size,
                              hipStream_t stream) {
    const float* X   = (const float*)d_in[0];
    const float* H   = (const float*)d_in[1];
    const float* e0W = (const float*)d_in[2];
    const float* e0b = (const float*)d_in[3];
    const float* e0s = (const float*)d_in[4];
    const float* e0t = (const float*)d_in[5];
    const float* e1W = (const float*)d_in[6];
    const float* e1b = (const float*)d_in[7];
    const float* e1s = (const float*)d_in[8];
    const float* e1t = (const float*)d_in[9];
    const float* c0W = (const float*)d_in[10];
    const float* c0b = (const float*)d_in[11];
    const float* c0s = (const float*)d_in[12];
    const float* c0t = (const float*)d_in[13];
    const float* c1W = (const float*)d_in[14];
    const float* c1b = (const float*)d_in[15];
    const float* c1s = (const float*)d_in[16];
    const float* c1t = (const float*)d_in[17];
    const float* n0W = (const float*)d_in[18];
    const float* n0b = (const float*)d_in[19];
    const float* n0s = (const float*)d_in[20];
    const float* n0t = (const float*)d_in[21];
    float* out = (float*)d_out;

    __bf16* G1 = (__bf16*)d_ws;                                   // 2*768*64 bf16 = 196608 B
    float*  G2 = (float*)((char*)d_ws + (size_t)Bn * Nn * DMm * 2); // 2*768*64 f32

    egnn_pre<<<dim3(48), dim3(TPB), 0, stream>>>(H, e0W, e0b, e0s, e0t, G1, G2);
    egnn_main<<<dim3(Bn * Nn), dim3(TPB), 0, stream>>>(X, H,
        e0W, e0s, e1W, e1b, e1s, e1t,
        c0W, c0b, c0s, c0t, c1W, c1b, c1s, c1t,
        n0W, n0b, n0s, n0t, G1, G2, out);
}

// Round 5
// 194.380 us; speedup vs baseline: 119.9096x; 1.0936x over previous
//
#include <hip/hip_runtime.h>
#include <hip/hip_bf16.h>

#define Bn  2
#define Nn  768
#define Dh  32
#define DMm 64
#define KK  16
#define TPB 256
#define SAB 176              // a1 staging row stride in BYTES (16B-aligned, bank-skewed)

typedef __bf16 bf16x8 __attribute__((ext_vector_type(8)));
typedef float  f32x4  __attribute__((ext_vector_type(4)));

// ws layout (bytes):
//   G1    bf16[2*768*64]   @ 0        (196608)
//   G2    f32 [2*768*64]   @ 196608   (393216)
//   W1f   bf16[4096]       @ 589824   (8192)   e1W folded, B-frag layout
//   W2Tf  bf16[4096]       @ 598016   (8192)   c0W^T folded, A-frag layout
//   o1v   f32[64]          @ 606208
//   o2w3  f32[2048]        @ 606464   (8192)   per-lane (o2,w3) pairs
//   Wnf   f32[3072]        @ 614656   (12288)  n0W folded
//   onOff f32[32]          @ 626944
//   wd2   f32[64]          @ 627072
//   misc  f32[4]           @ 627328   ([0]=c1off
// total 627392 B

// ---------------- phase 1: G1/G2 precompute (blocks 0..47) + weight packing (block 48)
__global__ __launch_bounds__(TPB) void egnn_pre(
    const float* __restrict__ H,  const float* __restrict__ e0W,
    const float* __restrict__ e0b, const float* __restrict__ e0s,
    const float* __restrict__ e0t,
    const float* __restrict__ e1W, const float* __restrict__ e1b,
    const float* __restrict__ e1s, const float* __restrict__ e1t,
    const float* __restrict__ c0W, const float* __restrict__ c0b,
    const float* __restrict__ c0s, const float* __restrict__ c0t,
    const float* __restrict__ c1W, const float* __restrict__ c1b,
    const float* __restrict__ c1s, const float* __restrict__ c1t,
    const float* __restrict__ n0W, const float* __restrict__ n0b,
    const float* __restrict__ n0s, const float* __restrict__ n0t,
    __bf16* __restrict__ G1, float* __restrict__ G2,
    __bf16* __restrict__ W1f, __bf16* __restrict__ W2Tf,
    float* __restrict__ o1v, float* __restrict__ o2w3,
    float* __restrict__ Wnf, float* __restrict__ onOff,
    float* __restrict__ wd2, float* __restrict__ misc)
{
    const int tid = threadIdx.x;
    if (blockIdx.x < 48) {
        __shared__ float sWa[Dh * DMm], sWb[Dh * DMm], sOff[DMm], sH[32 * Dh];
        for (int k = tid; k < Dh * DMm; k += TPB) {
            float s = e0s[k & 63];
            sWa[k] = e0W[k] * s;
            sWb[k] = e0W[Dh * DMm + k] * s;
        }
        if (tid < DMm) sOff[tid] = fmaf(e0b[tid], e0s[tid], e0t[tid]);
        const int row0 = blockIdx.x * 32;
        for (int k = tid; k < 32 * Dh; k += TPB) sH[k] = H[(size_t)row0 * Dh + k];
        __syncthreads();

        const int r = tid >> 3, g = tid & 7;
        float g1[8], g2[8];
        #pragma unroll
        for (int e = 0; e < 8; ++e) { g1[e] = 0.f; g2[e] = sOff[g * 8 + e]; }
        #pragma unroll
        for (int d = 0; d < Dh; ++d) {
            float hv = sH[r * Dh + d];
            #pragma unroll
            for (int e = 0; e < 8; ++e) {
                g1[e] = fmaf(hv, sWa[d * DMm + g * 8 + e], g1[e]);
                g2[e] = fmaf(hv, sWb[d * DMm + g * 8 + e], g2[e]);
            }
        }
        const size_t row = row0 + r;
        bf16x8 o;
        #pragma unroll
        for (int e = 0; e < 8; ++e) o[e] = (__bf16)g1[e];
        *(bf16x8*)(G1 + row * DMm + g * 8) = o;
        *(float4*)(G2 + row * DMm + g * 8)     = make_float4(g2[0], g2[1], g2[2], g2[3]);
        *(float4*)(G2 + row * DMm + g * 8 + 4) = make_float4(g2[4], g2[5], g2[6], g2[7]);
    } else {
        // ---- weight packing ----
        // W1f: B-frag layout: frag[(s*4+t4)*64 + lane][e] = W1'[k][n],
        //   k = s*32 + (lane>>4)*8 + e, n = t4*16 + (lane&15)
        for (int fi = tid; fi < 4096; fi += TPB) {
            int e = fi & 7, lane = (fi >> 3) & 63, t4 = (fi >> 9) & 3, s = fi >> 11;
            int k = s * 32 + (lane >> 4) * 8 + e;
            int n = t4 * 16 + (lane & 15);
            W1f[fi]  = (__bf16)(e1W[k * DMm + n] * e1s[n]);
            W2Tf[fi] = (__bf16)(c0W[k * DMm + n] * c0s[n]);   // A-frag of W2^T: A[m=n][k]
        }
        if (tid < DMm) {
            o1v[tid] = fmaf(e1b[tid], e1s[tid], e1t[tid]);
            wd2[tid] = e0W[64 * DMm + tid] * e0s[tid];
        }
        // o2w3: per-lane pairs: idx u=(lane,t4,r): ch = t4*16 + (lane>>4)*4 + r
        for (int u = tid; u < 1024; u += TPB) {
            int lane = u >> 4, rem = u & 15, t4 = rem >> 2, r = rem & 3;
            int ch = t4 * 16 + (lane >> 4) * 4 + r;
            o2w3[2 * u]     = fmaf(c0b[ch], c0s[ch], c0t[ch]);
            o2w3[2 * u + 1] = c1W[ch] * c1s[0];
        }
        for (int idx = tid; idx < (Dh + DMm) * Dh; idx += TPB)
            Wnf[idx] = n0W[idx] * n0s[idx & 31];
        if (tid < Dh) onOff[tid] = fmaf(n0b[tid], n0s[tid], n0t[tid]);
        if (tid == 0) misc[0] = fmaf(c1b[0], c1s[0], c1t[0]);
    }
}

// ---------------- phase 2: per-(b,i) fused edge MLP via MFMA + knn + outputs
__global__ __launch_bounds__(TPB, 2) void egnn_main(
    const float* __restrict__ X,  const float* __restrict__ H,
    const __bf16* __restrict__ G1, const float* __restrict__ G2,
    const __bf16* __restrict__ W1f, const __bf16* __restrict__ W2Tf,
    const float* __restrict__ o1v, const float* __restrict__ o2w3,
    const float* __restrict__ Wnf, const float* __restrict__ onOff,
    const float* __restrict__ wd2, const float* __restrict__ misc,
    float* __restrict__ out)
{
    const int bid = blockIdx.x;
    const int b = bid / Nn, i = bid % Nn;
    const int tid = threadIdx.x;
    const int wv = tid >> 6;
    const int lane = tid & 63;
    const int l15 = lane & 15;
    const int q   = lane >> 4;

    __shared__ float  sD2[Nn];
    __shared__ float  sDX[Nn * 3];
    __shared__ float  sWj[Nn];
    __shared__ int    sKnn[KK];
    __shared__ char   sHit[Nn];
    __shared__ float  sMnode[DMm];
    __shared__ float  sFeat[Dh + DMm];
    __shared__ float  sOutH[Dh];
    __shared__ float  sXacc[3], sXi[3];
    __shared__ __align__(16) char sA1[4][16 * SAB];   // per-wave a1 staging

    // ---- step 1: d2/xdiff + clears ----
    if (tid < DMm) sMnode[tid] = 0.f;
    if (tid < Dh)  { sOutH[tid] = 0.f; sFeat[tid] = H[(size_t)(b * Nn + i) * Dh + tid]; }
    if (tid < 3)   { sXi[tid] = X[(size_t)(b * Nn + i) * 3 + tid]; sXacc[tid] = 0.f; }
    {
        float xi0 = X[(size_t)(b * Nn + i) * 3 + 0];
        float xi1 = X[(size_t)(b * Nn + i) * 3 + 1];
        float xi2 = X[(size_t)(b * Nn + i) * 3 + 2];
        for (int j = tid; j < Nn; j += TPB) {
            float dx = X[(size_t)(b * Nn + j) * 3 + 0] - xi0;
            float dy = X[(size_t)(b * Nn + j) * 3 + 1] - xi1;
            float dz = X[(size_t)(b * Nn + j) * 3 + 2] - xi2;
            sDX[j * 3 + 0] = dx; sDX[j * 3 + 1] = dy; sDX[j * 3 + 2] = dz;
            sD2[j] = __fadd_rn(__fadd_rn(__fmul_rn(dx, dx), __fmul_rn(dy, dy)),
                               __fmul_rn(dz, dz));
            sHit[j] = 0;
        }
    }
    __syncthreads();

    // ---- step 2: wave 0 knn (register-resident; tie -> lower index) ----
    if (tid < 64) {
        float v[Nn / 64];
        #pragma unroll
        for (int k = 0; k < Nn / 64; ++k) v[k] = sD2[tid + (k << 6)];
        for (int r = 0; r < KK; ++r) {
            float bv = 3.4e38f; int bidx = Nn;
            #pragma unroll
            for (int k = 0; k < Nn / 64; ++k)
                if (v[k] < bv) { bv = v[k]; bidx = tid + (k << 6); }
            #pragma unroll
            for (int off = 32; off >= 1; off >>= 1) {
                float ov = __shfl_down(bv, off);
                int   oi = __shfl_down(bidx, off);
                if (ov < bv || (ov == bv && oi < bidx)) { bv = ov; bidx = oi; }
            }
            bidx = __shfl(bidx, 0);
            if (tid == 0) sKnn[r] = bidx;
            if ((bidx & 63) == tid) v[bidx >> 6] = 3.4e38f;
        }
        if (tid < KK) sHit[sKnn[tid]] = 1;
    }

    // ---- step 3: hoist per-lane constants (all from global, L2-hot) ----
    float g2c[2][8], wd2c[2][8];
    #pragma unroll
    for (int s = 0; s < 2; ++s) {
        const float4* gp = (const float4*)(G2 + (size_t)(b * Nn + i) * DMm + s * 32 + q * 8);
        float4 a = gp[0], c = gp[1];
        g2c[s][0] = a.x; g2c[s][1] = a.y; g2c[s][2] = a.z; g2c[s][3] = a.w;
        g2c[s][4] = c.x; g2c[s][5] = c.y; g2c[s][6] = c.z; g2c[s][7] = c.w;
        const float4* wp = (const float4*)(wd2 + s * 32 + q * 8);
        float4 wa = wp[0], wc = wp[1];
        wd2c[s][0] = wa.x; wd2c[s][1] = wa.y; wd2c[s][2] = wa.z; wd2c[s][3] = wa.w;
        wd2c[s][4] = wc.x; wd2c[s][5] = wc.y; wd2c[s][6] = wc.z; wd2c[s][7] = wc.w;
    }
    float o1c[4];
    #pragma unroll
    for (int t4 = 0; t4 < 4; ++t4) o1c[t4] = o1v[t4 * 16 + l15];
    float4 o2w3q[8];
    #pragma unroll
    for (int u = 0; u < 8; ++u)
        o2w3q[u] = ((const float4*)o2w3)[lane * 8 + u];
    const float c1off = misc[0];
    __syncthreads();   // sHit/sKnn visible to all waves

    // ---- step 4: j-tile loop ----
    for (int t = wv; t < Nn / 16; t += 4) {
        const int base = t * 16;
        const int jm = base + l15;

        // a0 A-fragments built in registers
        float d2v = sD2[jm];
        bf16x8 a0f[2];
        #pragma unroll
        for (int s = 0; s < 2; ++s) {
            bf16x8 g1v = *(const bf16x8*)(G1 + (size_t)(b * Nn + jm) * DMm + s * 32 + q * 8);
            bf16x8 af;
            #pragma unroll
            for (int e = 0; e < 8; ++e) {
                float v = fmaf(d2v, wd2c[s][e], g2c[s][e]) + (float)g1v[e];
                af[e] = (__bf16)fmaxf(v, 0.f);
            }
            a0f[s] = af;
        }

        // e1 GEMM (A=a0 rows=j, B=W1'): a1 = relu(a0 @ W1' + o1)
        f32x4 acc[4];
        #pragma unroll
        for (int t4 = 0; t4 < 4; ++t4) acc[t4] = f32x4{0.f, 0.f, 0.f, 0.f};
        #pragma unroll
        for (int s = 0; s < 2; ++s)
            #pragma unroll
            for (int t4 = 0; t4 < 4; ++t4) {
                bf16x8 w1 = *(const bf16x8*)(W1f + (((s * 4 + t4) * 64 + lane) << 3));
                acc[t4] = __builtin_amdgcn_mfma_f32_16x16x32_bf16(a0f[s], w1, acc[t4], 0, 0, 0);
            }
        // epilogue: relu + stage to LDS (row-major [j-within-tile][ch], skewed rows)
        #pragma unroll
        for (int t4 = 0; t4 < 4; ++t4)
            #pragma unroll
            for (int r = 0; r < 4; ++r) {
                float v = fmaxf(acc[t4][r] + o1c[t4], 0.f);
                acc[t4][r] = v;
                *(__bf16*)&sA1[wv][(q * 4 + r) * SAB + (t4 * 16 + l15) * 2] = (__bf16)v;
            }
        // m_node accumulation for knn rows (fp32 C-frags)
        #pragma unroll
        for (int r = 0; r < 4; ++r) {
            if (sHit[base + q * 4 + r]) {
                #pragma unroll
                for (int t4 = 0; t4 < 4; ++t4)
                    atomicAdd(&sMnode[t4 * 16 + l15], acc[t4][r]);
            }
        }
        // read a1^T B-fragments: B[k][n=l15] = a1[l15][k], k = s*32+q*8+e
        bf16x8 a1f[2];
        #pragma unroll
        for (int s = 0; s < 2; ++s)
            a1f[s] = *(const bf16x8*)&sA1[wv][l15 * SAB + s * 64 + q * 16];

        // c0 GEMM transposed (A=W2^T, B=a1^T): a2^T; lane holds 16 channels of j=base+l15
        f32x4 acc2[4];
        #pragma unroll
        for (int t4 = 0; t4 < 4; ++t4) acc2[t4] = f32x4{0.f, 0.f, 0.f, 0.f};
        #pragma unroll
        for (int s = 0; s < 2; ++s)
            #pragma unroll
            for (int t4 = 0; t4 < 4; ++t4) {
                bf16x8 w2 = *(const bf16x8*)(W2Tf + (((s * 4 + t4) * 64 + lane) << 3));
                acc2[t4] = __builtin_amdgcn_mfma_f32_16x16x32_bf16(w2, a1f[s], acc2[t4], 0, 0, 0);
            }
        // c1 dot fully in-lane, then 2-shfl reduce across q-groups
        float p = 0.f;
        #pragma unroll
        for (int t4 = 0; t4 < 4; ++t4)
            #pragma unroll
            for (int r = 0; r < 4; ++r) {
                int u = t4 * 4 + r;
                float4 qv = o2w3q[u >> 1];
                float o2 = (u & 1) ? qv.z : qv.x;
                float w3 = (u & 1) ? qv.w : qv.y;
                p = fmaf(fmaxf(acc2[t4][r] + o2, 0.f), w3, p);
            }
        p += __shfl_xor(p, 16);
        p += __shfl_xor(p, 32);
        if (lane < 16) sWj[base + l15] = fmaxf(p + c1off, 0.f);
    }
    __syncthreads();

    // ---- step 5: epilogues ----
    if (tid < DMm) sFeat[Dh + tid] = sMnode[tid];
    {
        float xa0 = 0.f, xa1 = 0.f, xa2 = 0.f;
        for (int j = tid; j < Nn; j += TPB) {
            float wvv = sWj[j];
            xa0 = fmaf(wvv, sDX[j * 3 + 0], xa0);
            xa1 = fmaf(wvv, sDX[j * 3 + 1], xa1);
            xa2 = fmaf(wvv, sDX[j * 3 + 2], xa2);
        }
        #pragma unroll
        for (int off = 32; off >= 1; off >>= 1) {
            xa0 += __shfl_down(xa0, off);
            xa1 += __shfl_down(xa1, off);
            xa2 += __shfl_down(xa2, off);
        }
        if (lane == 0) {
            atomicAdd(&sXacc[0], xa0);
            atomicAdd(&sXacc[1], xa1);
            atomicAdd(&sXacc[2], xa2);
        }
    }
    __syncthreads();
    // n0 layer: 256 threads = 32 out-channels x 8 k-partitions of 12
    {
        const int oc = tid & 31, part = tid >> 5;
        float z = 0.f;
        #pragma unroll
        for (int kk = 0; kk < 12; ++kk) {
            int c = part * 12 + kk;
            z = fmaf(sFeat[c], Wnf[c * Dh + oc], z);
        }
        atomicAdd(&sOutH[oc], z);
    }
    __syncthreads();
    if (tid < 3)
        out[(size_t)(b * Nn + i) * 3 + tid] = sXi[tid] + sXacc[tid];
    if (tid < Dh)
        out[(size_t)Bn * Nn * 3 + (size_t)(b * Nn + i) * Dh + tid] =
            fmaxf(sOutH[tid] + onOff[tid], 0.f);
}

extern "C" void kernel_launch(void* const* d_in, const int* in_sizes, int n_in,
                              void* d_out, int out_size, void* d_ws, size_t ws_size,
                              hipStream_t stream) {
    const float* X   = (const float*)d_in[0];
    const float* H   = (const float*)d_in[1];
    const float* e0W = (const float*)d_in[2];
    const float* e0b = (const float*)d_in[3];
    const float* e0s = (const float*)d_in[4];
    const float* e0t = (const float*)d_in[5];
    const float* e1W = (const float*)d_in[6];
    const float* e1b = (const float*)d_in[7];
    const float* e1s = (const float*)d_in[8];
    const float* e1t = (const float*)d_in[9];
    const float* c0W = (const float*)d_in[10];
    const float* c0b = (const float*)d_in[11];
    const float* c0s = (const float*)d_in[12];
    const float* c0t = (const float*)d_in[13];
    const float* c1W = (const float*)d_in[14];
    const float* c1b = (const float*)d_in[15];
    const float* c1s = (const float*)d_in[16];
    const float* c1t = (const float*)d_in[17];
    const float* n0W = (const float*)d_in[18];
    const float* n0b = (const float*)d_in[19];
    const float* n0s = (const float*)d_in[20];
    const float* n0t = (const float*)d_in[21];
    float* out = (float*)d_out;

    char* ws = (char*)d_ws;
    __bf16* G1   = (__bf16*)(ws);
    float*  G2   = (float*)(ws + 196608);
    __bf16* W1f  = (__bf16*)(ws + 589824);
    __bf16* W2Tf = (__bf16*)(ws + 598016);
    float*  o1v  = (float*)(ws + 606208);
    float*  o2w3 = (float*)(ws + 606464);
    float*  Wnf  = (float*)(ws + 614656);
    float*  onOff= (float*)(ws + 626944);
    float*  wd2  = (float*)(ws + 627072);
    float*  misc = (float*)(ws + 627328);

    egnn_pre<<<dim3(49), dim3(TPB), 0, stream>>>(H,
        e0W, e0b, e0s, e0t, e1W, e1b, e1s, e1t,
        c0W, c0b, c0s, c0t, c1W, c1b, c1s, c1t,
        n0W, n0b, n0s, n0t,
        G1, G2, W1f, W2Tf, o1v, o2w3, Wnf, onOff, wd2, misc);
    egnn_main<<<dim3(Bn * Nn), dim3(TPB), 0, stream>>>(X, H,
        G1, G2, W1f, W2Tf, o1v, o2w3, Wnf, onOff, wd2, misc, out);
}

// Round 6
// 162.676 us; speedup vs baseline: 143.2787x; 1.1949x over previous
//
#include <hip/hip_runtime.h>
#include <hip/hip_bf16.h>

#define Bn  2
#define Nn  768
#define Dh  32
#define DMm 64
#define KK  16
#define GI  6                // i's per main block
#define TPRE 256
#define TMAIN 512
#define SAB 176              // a1 staging row stride in BYTES (16B-aligned, bank-skewed)

typedef __bf16 bf16x8 __attribute__((ext_vector_type(8)));
typedef float  f32x4  __attribute__((ext_vector_type(4)));

// ws layout (bytes):
//   G1     bf16[98304]  @ 0        (196608)
//   G2     f32 [98304]  @ 196608   (393216)
//   W1f    bf16[4096]   @ 589824   (8192)
//   W2Tf   bf16[4096]   @ 598016   (8192)
//   o1v    f32[64]      @ 606208
//   o2w3   f32[2048]    @ 606464   (8192)
//   Wnf    f32[3072]    @ 614656   (12288)
//   onOff  f32[32]      @ 626944
//   wd2    f32[64]      @ 627072
//   misc   f32[4]       @ 627328
//   knnIdx int[24576]   @ 627456   (98304)  -> end 725760

// ---------------- phase 1: knn (blocks 0..383), G1/G2 (384..431), packing (432)
__global__ __launch_bounds__(TPRE) void egnn_pre(
    const float* __restrict__ X,  const float* __restrict__ H,
    const float* __restrict__ e0W, const float* __restrict__ e0b,
    const float* __restrict__ e0s, const float* __restrict__ e0t,
    const float* __restrict__ e1W, const float* __restrict__ e1b,
    const float* __restrict__ e1s, const float* __restrict__ e1t,
    const float* __restrict__ c0W, const float* __restrict__ c0b,
    const float* __restrict__ c0s, const float* __restrict__ c0t,
    const float* __restrict__ c1W, const float* __restrict__ c1b,
    const float* __restrict__ c1s, const float* __restrict__ c1t,
    const float* __restrict__ n0W, const float* __restrict__ n0b,
    const float* __restrict__ n0s, const float* __restrict__ n0t,
    __bf16* __restrict__ G1, float* __restrict__ G2,
    __bf16* __restrict__ W1f, __bf16* __restrict__ W2Tf,
    float* __restrict__ o1v, float* __restrict__ o2w3,
    float* __restrict__ Wnf, float* __restrict__ onOff,
    float* __restrict__ wd2, float* __restrict__ misc,
    int* __restrict__ knnIdx)
{
    const int tid = threadIdx.x;
    if (blockIdx.x < 384) {
        // ---- knn: one wave per i (row = b*768+i = global row index) ----
        const int lane = tid & 63;
        const int row_i = blockIdx.x * 4 + (tid >> 6);   // 0..1535
        const int b = row_i / Nn;
        const float xi0 = X[(size_t)row_i * 3 + 0];
        const float xi1 = X[(size_t)row_i * 3 + 1];
        const float xi2 = X[(size_t)row_i * 3 + 2];
        float v[Nn / 64];
        #pragma unroll
        for (int k = 0; k < Nn / 64; ++k) {
            int j = lane + (k << 6);
            size_t rj = (size_t)(b * Nn + j) * 3;
            float dx = X[rj + 0] - xi0;
            float dy = X[rj + 1] - xi1;
            float dz = X[rj + 2] - xi2;
            v[k] = __fadd_rn(__fadd_rn(__fmul_rn(dx, dx), __fmul_rn(dy, dy)),
                             __fmul_rn(dz, dz));
        }
        for (int r = 0; r < KK; ++r) {
            float bv = 3.4e38f; int bidx = Nn;
            #pragma unroll
            for (int k = 0; k < Nn / 64; ++k)
                if (v[k] < bv) { bv = v[k]; bidx = lane + (k << 6); }
            #pragma unroll
            for (int off = 32; off >= 1; off >>= 1) {
                float ov = __shfl_down(bv, off);
                int   oi = __shfl_down(bidx, off);
                if (ov < bv || (ov == bv && oi < bidx)) { bv = ov; bidx = oi; }
            }
            bidx = __shfl(bidx, 0);
            if (lane == 0) knnIdx[row_i * KK + r] = bidx;
            if ((bidx & 63) == lane) v[bidx >> 6] = 3.4e38f;
        }
    } else if (blockIdx.x < 432) {
        // ---- G1/G2: 48 blocks x 32 rows ----
        __shared__ float sWa[Dh * DMm], sWb[Dh * DMm], sOff[DMm], sH[32 * Dh];
        for (int k = tid; k < Dh * DMm; k += TPRE) {
            float s = e0s[k & 63];
            sWa[k] = e0W[k] * s;
            sWb[k] = e0W[Dh * DMm + k] * s;
        }
        if (tid < DMm) sOff[tid] = fmaf(e0b[tid], e0s[tid], e0t[tid]);
        const int row0 = (blockIdx.x - 384) * 32;
        for (int k = tid; k < 32 * Dh; k += TPRE) sH[k] = H[(size_t)row0 * Dh + k];
        __syncthreads();

        const int r = tid >> 3, g = tid & 7;
        float g1[8], g2[8];
        #pragma unroll
        for (int e = 0; e < 8; ++e) { g1[e] = 0.f; g2[e] = sOff[g * 8 + e]; }
        #pragma unroll
        for (int d = 0; d < Dh; ++d) {
            float hv = sH[r * Dh + d];
            #pragma unroll
            for (int e = 0; e < 8; ++e) {
                g1[e] = fmaf(hv, sWa[d * DMm + g * 8 + e], g1[e]);
                g2[e] = fmaf(hv, sWb[d * DMm + g * 8 + e], g2[e]);
            }
        }
        const size_t row = row0 + r;
        bf16x8 o;
        #pragma unroll
        for (int e = 0; e < 8; ++e) o[e] = (__bf16)g1[e];
        *(bf16x8*)(G1 + row * DMm + g * 8) = o;
        *(float4*)(G2 + row * DMm + g * 8)     = make_float4(g2[0], g2[1], g2[2], g2[3]);
        *(float4*)(G2 + row * DMm + g * 8 + 4) = make_float4(g2[4], g2[5], g2[6], g2[7]);
    } else {
        // ---- weight packing (src-coalesced loads, scatter stores) ----
        for (int src = tid; src < 4096; src += TPRE) {
            int k = src >> 6, n = src & 63;
            int fi = ((((k >> 5) * 4 + (n >> 4)) * 64) + ((k >> 3) & 3) * 16 + (n & 15)) * 8 + (k & 7);
            W1f[fi]  = (__bf16)(e1W[src] * e1s[n]);
            W2Tf[fi] = (__bf16)(c0W[src] * c0s[n]);
        }
        if (tid < DMm) {
            o1v[tid] = fmaf(e1b[tid], e1s[tid], e1t[tid]);
            wd2[tid] = e0W[64 * DMm + tid] * e0s[tid];
        }
        for (int u = tid; u < 1024; u += TPRE) {
            int lane = u >> 4, rem = u & 15, t4 = rem >> 2, r = rem & 3;
            int ch = t4 * 16 + (lane >> 4) * 4 + r;
            o2w3[2 * u]     = fmaf(c0b[ch], c0s[ch], c0t[ch]);
            o2w3[2 * u + 1] = c1W[ch] * c1s[0];
        }
        for (int idx = tid; idx < (Dh + DMm) * Dh; idx += TPRE)
            Wnf[idx] = n0W[idx] * n0s[idx & 31];
        if (tid < Dh) onOff[tid] = fmaf(n0b[tid], n0s[tid], n0t[tid]);
        if (tid == 0) misc[0] = fmaf(c1b[0], c1s[0], c1t[0]);
    }
}

// ---------------- phase 2: GI=6 i's per block, 8 waves
__global__ __launch_bounds__(TMAIN, 2) void egnn_main(
    const float* __restrict__ X,  const float* __restrict__ H,
    const __bf16* __restrict__ G1, const float* __restrict__ G2,
    const __bf16* __restrict__ W1f, const __bf16* __restrict__ W2Tf,
    const float* __restrict__ o1v, const float* __restrict__ o2w3,
    const float* __restrict__ Wnf, const float* __restrict__ onOff,
    const float* __restrict__ wd2, const float* __restrict__ misc,
    const int* __restrict__ knnIdx,
    float* __restrict__ out)
{
    const int bid = blockIdx.x;               // 0..255
    const int b  = bid >> 7;                  // 128 groups per batch
    const int i0 = (bid & 127) * GI;
    const int tid = threadIdx.x;
    const int wv = tid >> 6;                  // 0..7
    const int lane = tid & 63;
    const int l15 = lane & 15;
    const int q   = lane >> 4;

    __shared__ float  sX[Nn * 3];             // 9216
    __shared__ float  sD2[GI * Nn];           // 18432
    __shared__ float  sWj[GI * Nn];           // 18432
    __shared__ char   sHit[GI * Nn];          // 4608
    __shared__ float  sMnode[GI * DMm];       // 1536
    __shared__ float  sWn[(Dh + DMm) * Dh];   // 12288
    __shared__ float  sFeat[GI * 96];         // 2304
    __shared__ float  sOnOff[Dh];
    __shared__ float  sXacc[GI * 3];
    __shared__ __align__(16) char sA1[8][16 * SAB];  // 22528

    // ---- phase A1: staging + clears ----
    for (int k = tid; k < Nn * 3; k += TMAIN) sX[k] = X[(size_t)b * Nn * 3 + k];
    for (int k = tid; k < (Dh + DMm) * Dh; k += TMAIN) sWn[k] = Wnf[k];
    for (int k = tid; k < GI * Nn / 4; k += TMAIN) ((int*)sHit)[k] = 0;
    if (tid < GI * DMm) sMnode[tid] = 0.f;
    if (tid < Dh) sOnOff[tid] = onOff[tid];
    if (tid < GI * Dh) {
        int i_l = tid >> 5, c = tid & 31;
        sFeat[i_l * 96 + c] = H[(size_t)(b * Nn + i0 + i_l) * Dh + c];
    }
    __syncthreads();

    // ---- phase A2: d2 for GI i's + knn hit flags ----
    #pragma unroll
    for (int i_l = 0; i_l < GI; ++i_l) {
        float xi0 = sX[(i0 + i_l) * 3 + 0];
        float xi1 = sX[(i0 + i_l) * 3 + 1];
        float xi2 = sX[(i0 + i_l) * 3 + 2];
        for (int j = tid; j < Nn; j += TMAIN) {
            float dx = sX[j * 3 + 0] - xi0;
            float dy = sX[j * 3 + 1] - xi1;
            float dz = sX[j * 3 + 2] - xi2;
            sD2[i_l * Nn + j] = __fadd_rn(__fadd_rn(__fmul_rn(dx, dx), __fmul_rn(dy, dy)),
                                          __fmul_rn(dz, dz));
        }
    }
    if (tid < GI * KK) {
        int i_l = tid >> 4, r = tid & 15;
        int idx = knnIdx[(size_t)(b * Nn + i0 + i_l) * KK + r];
        sHit[i_l * Nn + idx] = 1;
    }

    // ---- hoist weight fragments + per-lane constants (registers) ----
    bf16x8 w1f[2][4], w2f[2][4];
    #pragma unroll
    for (int s = 0; s < 2; ++s)
        #pragma unroll
        for (int t4 = 0; t4 < 4; ++t4) {
            w1f[s][t4] = *(const bf16x8*)(W1f + (((s * 4 + t4) * 64 + lane) << 3));
            w2f[s][t4] = *(const bf16x8*)(W2Tf + (((s * 4 + t4) * 64 + lane) << 3));
        }
    float wd2c[2][8];
    #pragma unroll
    for (int s = 0; s < 2; ++s) {
        const float4* wp = (const float4*)(wd2 + s * 32 + q * 8);
        float4 wa = wp[0], wc = wp[1];
        wd2c[s][0] = wa.x; wd2c[s][1] = wa.y; wd2c[s][2] = wa.z; wd2c[s][3] = wa.w;
        wd2c[s][4] = wc.x; wd2c[s][5] = wc.y; wd2c[s][6] = wc.z; wd2c[s][7] = wc.w;
    }
    float o1c[4];
    #pragma unroll
    for (int t4 = 0; t4 < 4; ++t4) o1c[t4] = o1v[t4 * 16 + l15];
    float4 o2w3q[8];
    #pragma unroll
    for (int u = 0; u < 8; ++u) o2w3q[u] = ((const float4*)o2w3)[lane * 8 + u];
    const float c1off = misc[0];
    __syncthreads();

    // ---- main loop: GI*48 wave-iterations over (i_l, j-tile) ----
    for (int it = wv; it < GI * 48; it += 8) {
        const int i_l = it / 48;
        const int t = it - i_l * 48;
        const int base = t * 16;
        const int jm = base + l15;
        const int ig = i0 + i_l;

        float d2v = sD2[i_l * Nn + jm];

        // a0 A-fragments in registers
        bf16x8 a0f[2];
        #pragma unroll
        for (int s = 0; s < 2; ++s) {
            bf16x8 g1v = *(const bf16x8*)(G1 + (size_t)(b * Nn + jm) * DMm + s * 32 + q * 8);
            const float4* gp = (const float4*)(G2 + (size_t)(b * Nn + ig) * DMm + s * 32 + q * 8);
            float4 ga = gp[0], gc = gp[1];
            float g2c[8] = {ga.x, ga.y, ga.z, ga.w, gc.x, gc.y, gc.z, gc.w};
            bf16x8 af;
            #pragma unroll
            for (int e = 0; e < 8; ++e) {
                float v = fmaf(d2v, wd2c[s][e], g2c[e]) + (float)g1v[e];
                af[e] = (__bf16)fmaxf(v, 0.f);
            }
            a0f[s] = af;
        }

        // e1 GEMM
        f32x4 acc[4];
        #pragma unroll
        for (int t4 = 0; t4 < 4; ++t4) acc[t4] = f32x4{0.f, 0.f, 0.f, 0.f};
        #pragma unroll
        for (int s = 0; s < 2; ++s)
            #pragma unroll
            for (int t4 = 0; t4 < 4; ++t4)
                acc[t4] = __builtin_amdgcn_mfma_f32_16x16x32_bf16(a0f[s], w1f[s][t4], acc[t4], 0, 0, 0);
        #pragma unroll
        for (int t4 = 0; t4 < 4; ++t4)
            #pragma unroll
            for (int r = 0; r < 4; ++r) {
                float v = fmaxf(acc[t4][r] + o1c[t4], 0.f);
                acc[t4][r] = v;
                *(__bf16*)&sA1[wv][(q * 4 + r) * SAB + (t4 * 16 + l15) * 2] = (__bf16)v;
            }
        // m_node for knn rows (one b32 hit-word read, broadcast across l15)
        {
            unsigned hw = *(const unsigned*)&sHit[i_l * Nn + base + q * 4];
            if (hw) {
                #pragma unroll
                for (int r = 0; r < 4; ++r)
                    if ((hw >> (8 * r)) & 0xff) {
                        #pragma unroll
                        for (int t4 = 0; t4 < 4; ++t4)
                            atomicAdd(&sMnode[i_l * DMm + t4 * 16 + l15], acc[t4][r]);
                    }
            }
        }
        // a1^T B-fragments from wave-local staging
        bf16x8 a1f[2];
        #pragma unroll
        for (int s = 0; s < 2; ++s)
            a1f[s] = *(const bf16x8*)&sA1[wv][l15 * SAB + s * 64 + q * 16];

        // c0 GEMM (transposed) + fused c1 dot
        f32x4 acc2[4];
        #pragma unroll
        for (int t4 = 0; t4 < 4; ++t4) acc2[t4] = f32x4{0.f, 0.f, 0.f, 0.f};
        #pragma unroll
        for (int s = 0; s < 2; ++s)
            #pragma unroll
            for (int t4 = 0; t4 < 4; ++t4)
                acc2[t4] = __builtin_amdgcn_mfma_f32_16x16x32_bf16(w2f[s][t4], a1f[s], acc2[t4], 0, 0, 0);
        float p = 0.f;
        #pragma unroll
        for (int t4 = 0; t4 < 4; ++t4)
            #pragma unroll
            for (int r = 0; r < 4; ++r) {
                int u = t4 * 4 + r;
                float4 qv = o2w3q[u >> 1];
                float o2 = (u & 1) ? qv.z : qv.x;
                float w3 = (u & 1) ? qv.w : qv.y;
                p = fmaf(fmaxf(acc2[t4][r] + o2, 0.f), w3, p);
            }
        p += __shfl_xor(p, 16);
        p += __shfl_xor(p, 32);
        if (lane < 16) sWj[i_l * Nn + base + l15] = fmaxf(p + c1off, 0.f);
    }
    __syncthreads();

    // ---- epilogue 1: xacc (waves 0..5, one i each) + m_node -> sFeat ----
    if (wv < GI) {
        const int i_l = wv;
        float xi0 = sX[(i0 + i_l) * 3 + 0];
        float xi1 = sX[(i0 + i_l) * 3 + 1];
        float xi2 = sX[(i0 + i_l) * 3 + 2];
        float xa0 = 0.f, xa1 = 0.f, xa2 = 0.f;
        #pragma unroll
        for (int k = 0; k < Nn / 64; ++k) {
            int j = lane + (k << 6);
            float w = sWj[i_l * Nn + j];
            xa0 = fmaf(w, sX[j * 3 + 0] - xi0, xa0);
            xa1 = fmaf(w, sX[j * 3 + 1] - xi1, xa1);
            xa2 = fmaf(w, sX[j * 3 + 2] - xi2, xa2);
        }
        #pragma unroll
        for (int off = 32; off >= 1; off >>= 1) {
            xa0 += __shfl_down(xa0, off);
            xa1 += __shfl_down(xa1, off);
            xa2 += __shfl_down(xa2, off);
        }
        if (lane == 0) {
            sXacc[i_l * 3 + 0] = xa0;
            sXacc[i_l * 3 + 1] = xa1;
            sXacc[i_l * 3 + 2] = xa2;
        }
    }
    if (tid < GI * DMm) {
        int i_l = tid >> 6, ch = tid & 63;
        sFeat[i_l * 96 + Dh + ch] = sMnode[tid];
    }
    __syncthreads();

    // ---- epilogue 2: n0 layer + stores ----
    if (tid < GI * Dh) {
        int i_l = tid >> 5, oc = tid & 31;
        float z = sOnOff[oc];
        #pragma unroll
        for (int c = 0; c < Dh + DMm; ++c)
            z = fmaf(sFeat[i_l * 96 + c], sWn[c * Dh + oc], z);
        out[(size_t)Bn * Nn * 3 + (size_t)(b * Nn + i0 + i_l) * Dh + oc] = fmaxf(z, 0.f);
    }
    if (tid < GI * 3) {
        int i_l = tid / 3, c = tid - i_l * 3;
        out[(size_t)(b * Nn + i0 + i_l) * 3 + c] = sX[(i0 + i_l) * 3 + c] + sXacc[i_l * 3 + c];
    }
}

extern "C" void kernel_launch(void* const* d_in, const int* in_sizes, int n_in,
                              void* d_out, int out_size, void* d_ws, size_t ws_size,
                              hipStream_t stream) {
    const float* X   = (const float*)d_in[0];
    const float* H   = (const float*)d_in[1];
    const float* e0W = (const float*)d_in[2];
    const float* e0b = (const float*)d_in[3];
    const float* e0s = (const float*)d_in[4];
    const float* e0t = (const float*)d_in[5];
    const float* e1W = (const float*)d_in[6];
    const float* e1b = (const float*)d_in[7];
    const float* e1s = (const float*)d_in[8];
    const float* e1t = (const float*)d_in[9];
    const float* c0W = (const float*)d_in[10];
    const float* c0b = (const float*)d_in[11];
    const float* c0s = (const float*)d_in[12];
    const float* c0t = (const float*)d_in[13];
    const float* c1W = (const float*)d_in[14];
    const float* c1b = (const float*)d_in[15];
    const float* c1s = (const float*)d_in[16];
    const float* c1t = (const float*)d_in[17];
    const float* n0W = (const float*)d_in[18];
    const float* n0b = (const float*)d_in[19];
    const float* n0s = (const float*)d_in[20];
    const float* n0t = (const float*)d_in[21];
    float* out = (float*)d_out;

    char* ws = (char*)d_ws;
    __bf16* G1    = (__bf16*)(ws);
    float*  G2    = (float*)(ws + 196608);
    __bf16* W1f   = (__bf16*)(ws + 589824);
    __bf16* W2Tf  = (__bf16*)(ws + 598016);
    float*  o1v   = (float*)(ws + 606208);
    float*  o2w3  = (float*)(ws + 606464);
    float*  Wnf   = (float*)(ws + 614656);
    float*  onOff = (float*)(ws + 626944);
    float*  wd2   = (float*)(ws + 627072);
    float*  misc  = (float*)(ws + 627328);
    int*    knnIdx= (int*)(ws + 627456);

    egnn_pre<<<dim3(433), dim3(TPRE), 0, stream>>>(X, H,
        e0W, e0b, e0s, e0t, e1W, e1b, e1s, e1t,
        c0W, c0b, c0s, c0t, c1W, c1b, c1s, c1t,
        n0W, n0b, n0s, n0t,
        G1, G2, W1f, W2Tf, o1v, o2w3, Wnf, onOff, wd2, misc, knnIdx);
    egnn_main<<<dim3(Bn * Nn / GI), dim3(TMAIN), 0, stream>>>(X, H,
        G1, G2, W1f, W2Tf, o1v, o2w3, Wnf, onOff, wd2, misc, knnIdx, out);
}